// Round 1
// baseline (695.458 us; speedup 1.0000x reference)
//
#include <hip/hip_runtime.h>

#define ROWS 8192
#define KDIM 4096
#define NDIM 4096
#define KSEG 4
#define SEGK 1024  // KDIM / KSEG

// ws layout (floats):
//   w01  : [4096][16]      at offset 0          (65536 floats)
//   w23  : [16][4096]      at offset 65536      (65536 floats)
//   tpart: [4][8192][16]   at offset 131072     (524288 floats)

__device__ inline float4 fma4(float s, float4 w, float4 a) {
    a.x = fmaf(s, w.x, a.x);
    a.y = fmaf(s, w.y, a.y);
    a.z = fmaf(s, w.z, a.z);
    a.w = fmaf(s, w.w, a.w);
    return a;
}

// ---------------------------------------------------------------------------
// Build W01 (4096x16) and W23 (16x4096) from the four TT cores.
// W[i,j] = sum_{r1,r2,r3} c0[n0,r1] c1[r1,n1,r2] c2[r2,n2,r3] c3[r3,n3]
// with i = n0*64+n1, j = n2*64+n3.  Middle bond r2 has rank 16 -> W = W01@W23.
// ---------------------------------------------------------------------------
__global__ __launch_bounds__(256) void tt_prep(
    const float* __restrict__ c0, const float* __restrict__ c1,
    const float* __restrict__ c2, const float* __restrict__ c3,
    float* __restrict__ w01, float* __restrict__ w23)
{
    int gid = blockIdx.x * 256 + threadIdx.x;  // 0..131071
    if (gid < 65536) {
        // W01[p][r2], p = n0*64+n1
        int p = gid >> 4, r2 = gid & 15;
        int n0 = p >> 6, n1 = p & 63;
        float s = 0.f;
        #pragma unroll
        for (int r1 = 0; r1 < 16; ++r1)
            s = fmaf(c0[n0 * 16 + r1], c1[(r1 * 64 + n1) * 16 + r2], s);
        w01[gid] = s;
    } else {
        // W23[r2][j], j = n2*64+n3   (row-major 16x4096 so j is contiguous)
        int g = gid - 65536;
        int r2 = g >> 12, j = g & 4095;
        int n2 = j >> 6, n3 = j & 63;
        float s = 0.f;
        #pragma unroll
        for (int r3 = 0; r3 < 16; ++r3)
            s = fmaf(c2[(r2 * 64 + n2) * 16 + r3], c3[r3 * 64 + n3], s);
        w23[g] = s;
    }
}

// ---------------------------------------------------------------------------
// T = x @ W01  -> partials tpart[seg][row][16], seg = K/1024 segment.
// Block: 64 rows. Thread t: klane = t&15 (K 16-way), rowgrp = t>>4 (4 rows).
// Coalesced float4 x loads; 16-lane shfl_xor reduce at the end.
// ---------------------------------------------------------------------------
__global__ __launch_bounds__(256) void tt_xw01(
    const float* __restrict__ x, const float* __restrict__ w01,
    float* __restrict__ tpart)
{
    int mb  = blockIdx.x;   // 0..127, row blocks of 64
    int seg = blockIdx.y;   // 0..3
    int t = threadIdx.x;
    int klane = t & 15;
    int rg = t >> 4;
    int row0 = mb * 64 + rg * 4;
    const float* xb = x + (size_t)row0 * KDIM + seg * SEGK;

    float4 acc[4][4];  // [row][quarter of 16 r-values]
    #pragma unroll
    for (int a = 0; a < 4; ++a)
        #pragma unroll
        for (int q = 0; q < 4; ++q)
            acc[a][q] = make_float4(0.f, 0.f, 0.f, 0.f);

    for (int it = 0; it < SEGK / 64; ++it) {   // 16 iterations
        int kb = it * 64 + klane * 4;          // this thread's 4 k values
        const float* wp = w01 + (size_t)kb * 16;  // w01 offset for seg added below
        wp += (size_t)seg * SEGK * 16;
        float4 xv[4];
        #pragma unroll
        for (int rr = 0; rr < 4; ++rr)
            xv[rr] = *(const float4*)&xb[(size_t)rr * KDIM + kb];
        #pragma unroll
        for (int e = 0; e < 4; ++e) {
            float4 w0 = *(const float4*)&wp[e * 16 + 0];
            float4 w1 = *(const float4*)&wp[e * 16 + 4];
            float4 w2 = *(const float4*)&wp[e * 16 + 8];
            float4 w3 = *(const float4*)&wp[e * 16 + 12];
            #pragma unroll
            for (int rr = 0; rr < 4; ++rr) {
                float xe = ((const float*)&xv[rr])[e];
                acc[rr][0] = fma4(xe, w0, acc[rr][0]);
                acc[rr][1] = fma4(xe, w1, acc[rr][1]);
                acc[rr][2] = fma4(xe, w2, acc[rr][2]);
                acc[rr][3] = fma4(xe, w3, acc[rr][3]);
            }
        }
    }

    // Butterfly reduce across the 16 klane lanes (lane bits 0..3).
    #pragma unroll
    for (int m = 1; m <= 8; m <<= 1) {
        #pragma unroll
        for (int a = 0; a < 4; ++a)
            #pragma unroll
            for (int q = 0; q < 4; ++q) {
                acc[a][q].x += __shfl_xor(acc[a][q].x, m, 64);
                acc[a][q].y += __shfl_xor(acc[a][q].y, m, 64);
                acc[a][q].z += __shfl_xor(acc[a][q].z, m, 64);
                acc[a][q].w += __shfl_xor(acc[a][q].w, m, 64);
            }
    }

    // All 16 lanes now hold the full 4x16 sums. Lane klane writes
    // row e = klane>>2, quarter q = klane&3  (256 B contiguous per group).
    int e = klane >> 2, q = klane & 3;
    float* tp = tpart + ((size_t)seg * ROWS + row0 + e) * 16 + q * 4;
    *(float4*)tp = acc[e][q];
}

// ---------------------------------------------------------------------------
// out = T @ W23. Block: 16 rows (grid 512). Sum the 4 K-segment partials into
// LDS once, then sweep j with float4: W23 loads and out stores fully coalesced.
// ---------------------------------------------------------------------------
__global__ __launch_bounds__(256) void tt_tw23(
    const float* __restrict__ tpart, const float* __restrict__ w23,
    float* __restrict__ out)
{
    __shared__ float ts[16][16];
    int bb = blockIdx.x;
    int t = threadIdx.x;
    int i0 = bb * 16;
    {
        int row = t >> 4, r = t & 15;
        float s = 0.f;
        #pragma unroll
        for (int seg = 0; seg < KSEG; ++seg)
            s += tpart[((size_t)seg * ROWS + i0 + row) * 16 + r];
        ts[row][r] = s;
    }
    __syncthreads();

    for (int jt = 0; jt < 4; ++jt) {
        int j0 = jt * 1024 + t * 4;
        float4 w[16];
        #pragma unroll
        for (int r = 0; r < 16; ++r)
            w[r] = *(const float4*)&w23[r * 4096 + j0];
        #pragma unroll
        for (int row = 0; row < 16; ++row) {
            const float4* trp = (const float4*)&ts[row][0];
            float4 t0 = trp[0], t1 = trp[1], t2 = trp[2], t3 = trp[3];
            float4 a = make_float4(0.f, 0.f, 0.f, 0.f);
            a = fma4(t0.x, w[0],  a); a = fma4(t0.y, w[1],  a);
            a = fma4(t0.z, w[2],  a); a = fma4(t0.w, w[3],  a);
            a = fma4(t1.x, w[4],  a); a = fma4(t1.y, w[5],  a);
            a = fma4(t1.z, w[6],  a); a = fma4(t1.w, w[7],  a);
            a = fma4(t2.x, w[8],  a); a = fma4(t2.y, w[9],  a);
            a = fma4(t2.z, w[10], a); a = fma4(t2.w, w[11], a);
            a = fma4(t3.x, w[12], a); a = fma4(t3.y, w[13], a);
            a = fma4(t3.z, w[14], a); a = fma4(t3.w, w[15], a);
            *(float4*)&out[(size_t)(i0 + row) * 4096 + j0] = a;
        }
    }
}

extern "C" void kernel_launch(void* const* d_in, const int* in_sizes, int n_in,
                              void* d_out, int out_size, void* d_ws, size_t ws_size,
                              hipStream_t stream) {
    const float* x  = (const float*)d_in[0];
    const float* c0 = (const float*)d_in[1];
    const float* c1 = (const float*)d_in[2];
    const float* c2 = (const float*)d_in[3];
    const float* c3 = (const float*)d_in[4];
    float* out = (float*)d_out;

    float* w01   = (float*)d_ws;        // 65536 floats
    float* w23   = w01 + 65536;         // 65536 floats
    float* tpart = w23 + 65536;         // 4*8192*16 = 524288 floats

    tt_prep<<<512, 256, 0, stream>>>(c0, c1, c2, c3, w01, w23);
    tt_xw01<<<dim3(128, 4), 256, 0, stream>>>(x, w01, tpart);
    tt_tw23<<<512, 256, 0, stream>>>(tpart, w23, out);
}

// Round 2
// 204.107 us; speedup vs baseline: 3.4073x; 3.4073x over previous
//
#include <hip/hip_runtime.h>

#define ROWS 8192
#define KDIM 4096
#define NDIM 4096

// ws layout (floats):
//   w01  : [4096][16]        at offset 0          (65536 floats)
//   w23  : [16][4096]        at offset 65536      (65536 floats)
//   tpart: [kseg][8192][16]  at offset 131072     (kseg*131072 floats)

__device__ inline float4 fma4(float s, float4 w, float4 a) {
    a.x = fmaf(s, w.x, a.x);
    a.y = fmaf(s, w.y, a.y);
    a.z = fmaf(s, w.z, a.z);
    a.w = fmaf(s, w.w, a.w);
    return a;
}
__device__ inline float4 add4(float4 a, float4 b) {
    return make_float4(a.x + b.x, a.y + b.y, a.z + b.z, a.w + b.w);
}
__device__ inline float4 shfl_xor4(float4 v, int m) {
    v.x = __shfl_xor(v.x, m, 64);
    v.y = __shfl_xor(v.y, m, 64);
    v.z = __shfl_xor(v.z, m, 64);
    v.w = __shfl_xor(v.w, m, 64);
    return v;
}

// ---------------------------------------------------------------------------
// Build W01 (4096x16) and W23 (16x4096) from the four TT cores.
// Middle bond r2 has rank 16 -> W = W01 @ W23.
// ---------------------------------------------------------------------------
__global__ __launch_bounds__(256) void tt_prep(
    const float* __restrict__ c0, const float* __restrict__ c1,
    const float* __restrict__ c2, const float* __restrict__ c3,
    float* __restrict__ w01, float* __restrict__ w23)
{
    int gid = blockIdx.x * 256 + threadIdx.x;  // 0..131071
    if (gid < 65536) {
        // W01[p][r2], p = n0*64+n1
        int p = gid >> 4, r2 = gid & 15;
        int n0 = p >> 6, n1 = p & 63;
        float s = 0.f;
        #pragma unroll
        for (int r1 = 0; r1 < 16; ++r1)
            s = fmaf(c0[n0 * 16 + r1], c1[(r1 * 64 + n1) * 16 + r2], s);
        w01[gid] = s;
    } else {
        // W23[r2][j], j = n2*64+n3  (row-major 16x4096, j contiguous)
        int g = gid - 65536;
        int r2 = g >> 12, j = g & 4095;
        int n2 = j >> 6, n3 = j & 63;
        float s = 0.f;
        #pragma unroll
        for (int r3 = 0; r3 < 16; ++r3)
            s = fmaf(c2[(r2 * 64 + n2) * 16 + r3], c3[r3 * 64 + n3], s);
        w23[g] = s;
    }
}

// ---------------------------------------------------------------------------
// T = x @ W01 -> tpart[seg][row][16].
// Block: 64 rows, 256 thr. Thread: klane=t&15 (K 16-way), rg=t>>4 (4 rows).
// Reduce-scatter butterfly over klane (static indices only -> no scratch).
// ---------------------------------------------------------------------------
template <int NIT>
__global__ __launch_bounds__(256) void tt_xw01(
    const float* __restrict__ x, const float* __restrict__ w01,
    float* __restrict__ tpart)
{
    int mb  = blockIdx.x;   // row block of 64
    int seg = blockIdx.y;   // K segment
    int t = threadIdx.x;
    int klane = t & 15;
    int rg = t >> 4;
    int row0 = mb * 64 + rg * 4;
    const int segk = NIT * 64;
    const float* xb = x + (size_t)row0 * KDIM + seg * segk;
    const float* wb = w01 + (size_t)seg * segk * 16;

    float4 acc[4][4];  // [row][quarter of 16 r2-values]
    #pragma unroll
    for (int a = 0; a < 4; ++a)
        #pragma unroll
        for (int q = 0; q < 4; ++q)
            acc[a][q] = make_float4(0.f, 0.f, 0.f, 0.f);

    #pragma unroll
    for (int it = 0; it < NIT; ++it) {
        int kb = it * 64 + klane * 4;          // this thread's 4 k values
        const float* wp = wb + (size_t)kb * 16;
        float4 xv[4];
        #pragma unroll
        for (int rr = 0; rr < 4; ++rr)
            xv[rr] = *(const float4*)&xb[(size_t)rr * KDIM + kb];
        #pragma unroll
        for (int e = 0; e < 4; ++e) {
            float4 w0 = *(const float4*)&wp[e * 16 + 0];
            float4 w1 = *(const float4*)&wp[e * 16 + 4];
            float4 w2 = *(const float4*)&wp[e * 16 + 8];
            float4 w3 = *(const float4*)&wp[e * 16 + 12];
            #pragma unroll
            for (int rr = 0; rr < 4; ++rr) {
                float xe = ((const float*)&xv[rr])[e];
                acc[rr][0] = fma4(xe, w0, acc[rr][0]);
                acc[rr][1] = fma4(xe, w1, acc[rr][1]);
                acc[rr][2] = fma4(xe, w2, acc[rr][2]);
                acc[rr][3] = fma4(xe, w3, acc[rr][3]);
            }
        }
    }

    // Reduce-scatter butterfly over klane bits 3..0. Runtime ternary
    // CONDITIONS, compile-time array INDICES -> cndmask selects, no scratch.
    const bool b3 = klane & 8, b2 = klane & 4, b1 = klane & 2, b0 = klane & 1;

    float4 s0[2][4];  // kept row pair (base = b3*2)
    #pragma unroll
    for (int q = 0; q < 4; ++q)
        #pragma unroll
        for (int j = 0; j < 2; ++j) {
            float4 send = b3 ? acc[j][q]     : acc[2 + j][q];
            float4 keep = b3 ? acc[2 + j][q] : acc[j][q];
            s0[j][q] = add4(keep, shfl_xor4(send, 8));
        }
    float4 s1[4];     // kept row (= b3*2 + b2), all 4 quarters
    #pragma unroll
    for (int q = 0; q < 4; ++q) {
        float4 send = b2 ? s0[0][q] : s0[1][q];
        float4 keep = b2 ? s0[1][q] : s0[0][q];
        s1[q] = add4(keep, shfl_xor4(send, 4));
    }
    float4 s2[2];     // kept quarter pair (base = b1*2)
    #pragma unroll
    for (int j = 0; j < 2; ++j) {
        float4 send = b1 ? s1[j]     : s1[2 + j];
        float4 keep = b1 ? s1[2 + j] : s1[j];
        s2[j] = add4(keep, shfl_xor4(send, 2));
    }
    float4 send = b0 ? s2[0] : s2[1];
    float4 keep = b0 ? s2[1] : s2[0];
    float4 res  = add4(keep, shfl_xor4(send, 1));

    // Lane klane holds row e = klane>>2, quarter q = klane&3, fully summed.
    int e = klane >> 2, q = klane & 3;
    float* tp = tpart + ((size_t)seg * ROWS + row0 + e) * 16 + q * 4;
    *(float4*)tp = res;
}

// ---------------------------------------------------------------------------
// out = T @ W23. Block: 16 rows (grid 512). Sum K-segment partials into LDS,
// then sweep j with float4: W23 loads and out stores fully coalesced.
// ---------------------------------------------------------------------------
__global__ __launch_bounds__(256) void tt_tw23(
    const float* __restrict__ tpart, const float* __restrict__ w23,
    float* __restrict__ out, int nseg)
{
    __shared__ float ts[16][16];
    int bb = blockIdx.x;
    int t = threadIdx.x;
    int i0 = bb * 16;
    {
        int row = t >> 4, r = t & 15;
        float s = 0.f;
        for (int seg = 0; seg < nseg; ++seg)
            s += tpart[((size_t)seg * ROWS + i0 + row) * 16 + r];
        ts[row][r] = s;
    }
    __syncthreads();

    for (int jt = 0; jt < 4; ++jt) {
        int j0 = jt * 1024 + t * 4;
        float4 w[16];
        #pragma unroll
        for (int r = 0; r < 16; ++r)
            w[r] = *(const float4*)&w23[r * 4096 + j0];
        #pragma unroll
        for (int row = 0; row < 16; ++row) {
            const float4* trp = (const float4*)&ts[row][0];
            float4 t0 = trp[0], t1 = trp[1], t2 = trp[2], t3 = trp[3];
            float4 a = make_float4(0.f, 0.f, 0.f, 0.f);
            a = fma4(t0.x, w[0],  a); a = fma4(t0.y, w[1],  a);
            a = fma4(t0.z, w[2],  a); a = fma4(t0.w, w[3],  a);
            a = fma4(t1.x, w[4],  a); a = fma4(t1.y, w[5],  a);
            a = fma4(t1.z, w[6],  a); a = fma4(t1.w, w[7],  a);
            a = fma4(t2.x, w[8],  a); a = fma4(t2.y, w[9],  a);
            a = fma4(t2.z, w[10], a); a = fma4(t2.w, w[11], a);
            a = fma4(t3.x, w[12], a); a = fma4(t3.y, w[13], a);
            a = fma4(t3.z, w[14], a); a = fma4(t3.w, w[15], a);
            *(float4*)&out[(size_t)(i0 + row) * 4096 + j0] = a;
        }
    }
}

extern "C" void kernel_launch(void* const* d_in, const int* in_sizes, int n_in,
                              void* d_out, int out_size, void* d_ws, size_t ws_size,
                              hipStream_t stream) {
    const float* x  = (const float*)d_in[0];
    const float* c0 = (const float*)d_in[1];
    const float* c1 = (const float*)d_in[2];
    const float* c2 = (const float*)d_in[3];
    const float* c3 = (const float*)d_in[4];
    float* out = (float*)d_out;

    float* w01   = (float*)d_ws;        // 65536 floats
    float* w23   = w01 + 65536;         // 65536 floats
    float* tpart = w23 + 65536;         // kseg * 131072 floats

    // 8-way K split if workspace allows (4.72 MB), else 4-way (2.62 MB).
    const size_t need8 = (size_t)(131072 + 8 * 131072) * 4;
    const int kseg = (ws_size >= need8) ? 8 : 4;

    tt_prep<<<512, 256, 0, stream>>>(c0, c1, c2, c3, w01, w23);
    if (kseg == 8)
        tt_xw01<8><<<dim3(128, 8), 256, 0, stream>>>(x, w01, tpart);
    else
        tt_xw01<16><<<dim3(128, 4), 256, 0, stream>>>(x, w01, tpart);
    tt_tw23<<<512, 256, 0, stream>>>(tpart, w23, out, kseg);
}

// Round 3
// 105.154 us; speedup vs baseline: 6.6137x; 1.9410x over previous
//
#include <hip/hip_runtime.h>

#define ROWS 8192
#define KDIM 4096
#define NDIM 4096

typedef float f32x4 __attribute__((ext_vector_type(4)));

// ws layout (floats):
//   w01  : [4096][16]        at offset 0          (65536 floats)
//   w23  : [16][4096]        at offset 65536      (65536 floats)
//   tpart: [kseg][8192][16]  at offset 131072     (kseg*131072 floats)

__device__ inline f32x4 fma4(float s, f32x4 w, f32x4 a) {
    a.x = fmaf(s, w.x, a.x);
    a.y = fmaf(s, w.y, a.y);
    a.z = fmaf(s, w.z, a.z);
    a.w = fmaf(s, w.w, a.w);
    return a;
}
__device__ inline f32x4 add4(f32x4 a, f32x4 b) { return a + b; }
__device__ inline f32x4 shfl_xor4(f32x4 v, int m) {
    v.x = __shfl_xor(v.x, m, 64);
    v.y = __shfl_xor(v.y, m, 64);
    v.z = __shfl_xor(v.z, m, 64);
    v.w = __shfl_xor(v.w, m, 64);
    return v;
}

// ---------------------------------------------------------------------------
// Build W01 (4096x16) and W23 (16x4096) from the four TT cores.
// Middle bond r2 has rank 16 -> W = W01 @ W23.
// ---------------------------------------------------------------------------
__global__ __launch_bounds__(256) void tt_prep(
    const float* __restrict__ c0, const float* __restrict__ c1,
    const float* __restrict__ c2, const float* __restrict__ c3,
    float* __restrict__ w01, float* __restrict__ w23)
{
    int gid = blockIdx.x * 256 + threadIdx.x;  // 0..131071
    if (gid < 65536) {
        // W01[p][r2], p = n0*64+n1
        int p = gid >> 4, r2 = gid & 15;
        int n0 = p >> 6, n1 = p & 63;
        float s = 0.f;
        #pragma unroll
        for (int r1 = 0; r1 < 16; ++r1)
            s = fmaf(c0[n0 * 16 + r1], c1[(r1 * 64 + n1) * 16 + r2], s);
        w01[gid] = s;
    } else {
        // W23[r2][j], j = n2*64+n3  (row-major 16x4096, j contiguous)
        int g = gid - 65536;
        int r2 = g >> 12, j = g & 4095;
        int n2 = j >> 6, n3 = j & 63;
        float s = 0.f;
        #pragma unroll
        for (int r3 = 0; r3 < 16; ++r3)
            s = fmaf(c2[(r2 * 64 + n2) * 16 + r3], c3[r3 * 64 + n3], s);
        w23[g] = s;
    }
}

// ---------------------------------------------------------------------------
// T = x @ W01 -> tpart[seg][row][16].
// Block: 64 rows, 256 thr. Thread: klane=t&15 (K 16-way), rg=t>>4 (4 rows).
// Reduce-scatter butterfly over klane (static indices only -> no scratch).
// ---------------------------------------------------------------------------
template <int NIT>
__global__ __launch_bounds__(256) void tt_xw01(
    const float* __restrict__ x, const float* __restrict__ w01,
    float* __restrict__ tpart)
{
    int mb  = blockIdx.x;   // row block of 64
    int seg = blockIdx.y;   // K segment
    int t = threadIdx.x;
    int klane = t & 15;
    int rg = t >> 4;
    int row0 = mb * 64 + rg * 4;
    const int segk = NIT * 64;
    const float* xb = x + (size_t)row0 * KDIM + seg * segk;
    const float* wb = w01 + (size_t)seg * segk * 16;

    f32x4 acc[4][4];  // [row][quarter of 16 r2-values]
    #pragma unroll
    for (int a = 0; a < 4; ++a)
        #pragma unroll
        for (int q = 0; q < 4; ++q)
            acc[a][q] = (f32x4)(0.f);

    #pragma unroll
    for (int it = 0; it < NIT; ++it) {
        int kb = it * 64 + klane * 4;          // this thread's 4 k values
        const float* wp = wb + (size_t)kb * 16;
        f32x4 xv[4];
        #pragma unroll
        for (int rr = 0; rr < 4; ++rr)
            xv[rr] = __builtin_nontemporal_load(
                (const f32x4*)&xb[(size_t)rr * KDIM + kb]);
        #pragma unroll
        for (int e = 0; e < 4; ++e) {
            f32x4 w0 = *(const f32x4*)&wp[e * 16 + 0];
            f32x4 w1 = *(const f32x4*)&wp[e * 16 + 4];
            f32x4 w2 = *(const f32x4*)&wp[e * 16 + 8];
            f32x4 w3 = *(const f32x4*)&wp[e * 16 + 12];
            #pragma unroll
            for (int rr = 0; rr < 4; ++rr) {
                float xe = xv[rr][e];
                acc[rr][0] = fma4(xe, w0, acc[rr][0]);
                acc[rr][1] = fma4(xe, w1, acc[rr][1]);
                acc[rr][2] = fma4(xe, w2, acc[rr][2]);
                acc[rr][3] = fma4(xe, w3, acc[rr][3]);
            }
        }
    }

    // Reduce-scatter butterfly over klane bits 3..0. Runtime ternary
    // CONDITIONS, compile-time array INDICES -> cndmask selects, no scratch.
    const bool b3 = klane & 8, b2 = klane & 4, b1 = klane & 2, b0 = klane & 1;

    f32x4 s0[2][4];  // kept row pair (base = b3*2)
    #pragma unroll
    for (int q = 0; q < 4; ++q)
        #pragma unroll
        for (int j = 0; j < 2; ++j) {
            f32x4 send = b3 ? acc[j][q]     : acc[2 + j][q];
            f32x4 keep = b3 ? acc[2 + j][q] : acc[j][q];
            s0[j][q] = add4(keep, shfl_xor4(send, 8));
        }
    f32x4 s1[4];     // kept row (= b3*2 + b2), all 4 quarters
    #pragma unroll
    for (int q = 0; q < 4; ++q) {
        f32x4 send = b2 ? s0[0][q] : s0[1][q];
        f32x4 keep = b2 ? s0[1][q] : s0[0][q];
        s1[q] = add4(keep, shfl_xor4(send, 4));
    }
    f32x4 s2[2];     // kept quarter pair (base = b1*2)
    #pragma unroll
    for (int j = 0; j < 2; ++j) {
        f32x4 send = b1 ? s1[j]     : s1[2 + j];
        f32x4 keep = b1 ? s1[2 + j] : s1[j];
        s2[j] = add4(keep, shfl_xor4(send, 2));
    }
    f32x4 send = b0 ? s2[0] : s2[1];
    f32x4 keep = b0 ? s2[1] : s2[0];
    f32x4 res  = add4(keep, shfl_xor4(send, 1));

    // Lane klane holds row e = klane>>2, quarter q = klane&3, fully summed.
    int e = klane >> 2, q = klane & 3;
    float* tp = tpart + ((size_t)seg * ROWS + row0 + e) * 16 + q * 4;
    *(f32x4*)tp = res;
}

// ---------------------------------------------------------------------------
// out = T @ W23. Block: 16 rows x 1024 cols; grid (512, 4) = 2048 blocks.
// Thread owns ONE j-quad: w[16] in regs (64 VGPR), row loop unroll 2 keeps
// live state bounded. Nontemporal out stores (134 MB stream).
// ---------------------------------------------------------------------------
__global__ __launch_bounds__(256) void tt_tw23(
    const float* __restrict__ tpart, const float* __restrict__ w23,
    float* __restrict__ out, int nseg)
{
    __shared__ float ts[16][16];
    int rb = blockIdx.x;   // row block of 16
    int jb = blockIdx.y;   // col block of 1024
    int t = threadIdx.x;
    int i0 = rb * 16;
    {
        int row = t >> 4, r = t & 15;
        float s = 0.f;
        for (int seg = 0; seg < nseg; ++seg)
            s += tpart[((size_t)seg * ROWS + i0 + row) * 16 + r];
        ts[row][r] = s;
    }
    __syncthreads();

    int j0 = jb * 1024 + t * 4;
    f32x4 w[16];
    #pragma unroll
    for (int r = 0; r < 16; ++r)
        w[r] = *(const f32x4*)&w23[r * 4096 + j0];

    #pragma unroll 2
    for (int row = 0; row < 16; ++row) {
        const f32x4* trp = (const f32x4*)&ts[row][0];
        f32x4 t0 = trp[0], t1 = trp[1], t2 = trp[2], t3 = trp[3];
        f32x4 a = (f32x4)(0.f);
        a = fma4(t0.x, w[0],  a); a = fma4(t0.y, w[1],  a);
        a = fma4(t0.z, w[2],  a); a = fma4(t0.w, w[3],  a);
        a = fma4(t1.x, w[4],  a); a = fma4(t1.y, w[5],  a);
        a = fma4(t1.z, w[6],  a); a = fma4(t1.w, w[7],  a);
        a = fma4(t2.x, w[8],  a); a = fma4(t2.y, w[9],  a);
        a = fma4(t2.z, w[10], a); a = fma4(t2.w, w[11], a);
        a = fma4(t3.x, w[12], a); a = fma4(t3.y, w[13], a);
        a = fma4(t3.z, w[14], a); a = fma4(t3.w, w[15], a);
        __builtin_nontemporal_store(a, (f32x4*)&out[(size_t)(i0 + row) * 4096 + j0]);
    }
}

extern "C" void kernel_launch(void* const* d_in, const int* in_sizes, int n_in,
                              void* d_out, int out_size, void* d_ws, size_t ws_size,
                              hipStream_t stream) {
    const float* x  = (const float*)d_in[0];
    const float* c0 = (const float*)d_in[1];
    const float* c1 = (const float*)d_in[2];
    const float* c2 = (const float*)d_in[3];
    const float* c3 = (const float*)d_in[4];
    float* out = (float*)d_out;

    float* w01   = (float*)d_ws;        // 65536 floats
    float* w23   = w01 + 65536;         // 65536 floats
    float* tpart = w23 + 65536;         // kseg * 131072 floats

    // Pick K-split by available workspace: 16 (8.9 MB) > 8 (4.7 MB) > 4.
    const size_t f = sizeof(float);
    int kseg;
    if      (ws_size >= (size_t)(131072 + 16 * 131072) * f) kseg = 16;
    else if (ws_size >= (size_t)(131072 +  8 * 131072) * f) kseg = 8;
    else                                                    kseg = 4;

    tt_prep<<<512, 256, 0, stream>>>(c0, c1, c2, c3, w01, w23);
    if (kseg == 16)
        tt_xw01<4><<<dim3(128, 16), 256, 0, stream>>>(x, w01, tpart);
    else if (kseg == 8)
        tt_xw01<8><<<dim3(128, 8), 256, 0, stream>>>(x, w01, tpart);
    else
        tt_xw01<16><<<dim3(128, 4), 256, 0, stream>>>(x, w01, tpart);
    tt_tw23<<<dim3(512, 4), 256, 0, stream>>>(tpart, w23, out, kseg);
}